// Round 2
// baseline (297.507 us; speedup 1.0000x reference)
//
#include <hip/hip_runtime.h>
#include <hip/hip_cooperative_groups.h>
#include <math.h>

namespace cg = cooperative_groups;

#define POOLED      7
#define OUTPUT_DIM  21
#define GROUP       7
#define CHANNELS    (OUTPUT_DIM * GROUP * GROUP)   // 1029
#define FH          64
#define FW          64
#define PLANE       (FH * FW)                      // 4096 floats, 16 KB
#define NUM_ROIS    1024
#define SCALE       0.0625f
#define GRID_COOP   512                            // 2 blocks/CU x 256 CU (64 KB LDS each)

// Opaque VGPR pin: blocks FMA contraction (hipcc -ffp-contract=fast ignores
// `#pragma clang fp contract(off)`). CORRECTNESS-CRITICAL: the golden's
// boundary chain is f32, separately rounded, with bin = roi * RN(1/7)
// (reciprocal multiply) — verified round 10, absmax 3.9e-3. Do not change.
__device__ __forceinline__ float freeze(float x) {
    __asm__ volatile("" : "+v"(x));
    return x;
}

// ROI-dependent (channel-independent) prefix of the frozen chain — hoisted
// out of the per-channel loop. Ops are bit-identical to the verified chain.
struct RoiGeom { int b; float start_h, start_w, bin_h, bin_w; };

__device__ __forceinline__ RoiGeom roi_geom(const float* __restrict__ rois, int t) {
    const float* r = rois + t * 5;
    RoiGeom g;
    g.b = (int)r[0];
    float start_w = rintf(r[1]) * SCALE;          // np.round = half-even
    float start_h = rintf(r[2]) * SCALE;
    float end_w   = rintf(r[3] + 1.0f) * SCALE;
    float end_h   = rintf(r[4] + 1.0f) * SCALE;
    float roi_w = fmaxf(end_w - start_w, 0.1f);
    float roi_h = fmaxf(end_h - start_h, 0.1f);
    const float inv7 = 1.0f / 7.0f;               // RN(1/7)
    g.bin_h = freeze(roi_h * inv7);               // reciprocal multiply
    g.bin_w = freeze(roi_w * inv7);
    g.start_h = start_h;
    g.start_w = start_w;
    return g;
}

// ph/pw-dependent tail of the frozen chain + LDS region sum.
__device__ __forceinline__ float bin_value(const RoiGeom& g, int ph, int pw,
                                           const float* __restrict__ pl) {
    float mh0 = freeze((float)ph * g.bin_h);      // separate mul, then add
    float mh1 = freeze((float)(ph + 1) * g.bin_h);
    float mw0 = freeze((float)pw * g.bin_w);
    float mw1 = freeze((float)(pw + 1) * g.bin_w);

    float hs_f = floorf(mh0 + g.start_h);
    float he_f = ceilf (mh1 + g.start_h);
    float ws_f = floorf(mw0 + g.start_w);
    float we_f = ceilf (mw1 + g.start_w);

    int hs = (int)fminf(fmaxf(hs_f, 0.0f), (float)FH);
    int he = (int)fminf(fmaxf(he_f, 0.0f), (float)FH);
    int ws = (int)fminf(fmaxf(ws_f, 0.0f), (float)FW);
    int we = (int)fminf(fmaxf(we_f, 0.0f), (float)FW);

    const float* base = pl + g.b * PLANE;
    float s = 0.0f;
    for (int h = hs; h < he; ++h) {
        const float* row = base + h * FW;
        for (int w = ws; w < we; ++w) s += row[w];
    }
    int area = (he - hs) * (we - ws);
    return (area <= 0) ? 0.0f : s / (float)area;
}

// FUSED COOPERATIVE KERNEL (round 13): phase 1 = bin-major LDS-staged pooling
// into ws[c][n] (coalesced 4 KB rows); grid.sync; phase 2 = tiled transpose
// ws -> out[n][c]. Removes the second launch + inter-kernel graph gap that
// dominated the remaining non-HBM time, and amortizes the old 2.01-round
// grid tail (512 blocks, blocks 0..4 take a 3rd channel).
__global__ __launch_bounds__(1024)
void psroi_fused(const float* __restrict__ feat,
                 const float* __restrict__ rois,
                 float* __restrict__ ws,
                 float* __restrict__ out) {
    __shared__ float pl[4 * PLANE];       // 64 KB: 4 batch planes of one channel
    const int t   = threadIdx.x;          // 0..1023 == ROI index in phase 1
    const int bid = blockIdx.x;

    const RoiGeom g = roi_geom(rois, t);  // hoisted: channel-independent

    for (int c = bid; c < CHANNELS; c += GRID_COOP) {
        const int pw = c % 7;
        const int ph = (c / 7) % 7;

        // Stage 4 batch planes of channel c: coalesced float4, exactly-once.
#pragma unroll
        for (int bb = 0; bb < 4; ++bb) {
            const float4* src = reinterpret_cast<const float4*>(
                feat + ((size_t)bb * CHANNELS + c) * PLANE);
            reinterpret_cast<float4*>(pl + bb * PLANE)[t] = src[t];
        }
        __syncthreads();

        float v = bin_value(g, ph, pw, pl);
        ws[(size_t)c * NUM_ROIS + t] = v;         // coalesced 4 KB row

        __syncthreads();                          // reads done before re-stage
    }

    __threadfence();                              // ws visible device-wide (XCDs)
    cg::this_grid().sync();

    // Phase 2: transpose ws[1029][1024] -> out[1024][1029].
    // 17 x 16 = 272 tiles of 64x64; blocks 0..271 take one tile each.
    if (bid < 17 * 16) {
        const int c0 = (bid % 17) * 64;
        const int n0 = (bid / 17) * 64;
        float (*tile)[65] = reinterpret_cast<float (*)[65]>(pl);
        const int tx = t & 63;                    // n within tile (load) / c (store)
        const int ty = t >> 6;                    // 0..15

#pragma unroll
        for (int i = 0; i < 64; i += 16) {
            const int cc = c0 + ty + i;
            if (cc < CHANNELS)
                tile[ty + i][tx] = ws[(size_t)cc * NUM_ROIS + (n0 + tx)];
        }
        __syncthreads();
#pragma unroll
        for (int i = 0; i < 64; i += 16) {
            const int nn = n0 + ty + i;
            const int cc = c0 + tx;
            if (cc < CHANNELS)
                out[(size_t)nn * CHANNELS + cc] = tile[tx][ty + i];  // 256B runs
        }
    }
}

// ---------- fallback path (round-12 verified two-kernel pipeline) ----------
template<bool TO_WS>
__global__ __launch_bounds__(1024)
void psroi_lds(const float* __restrict__ feat,
               const float* __restrict__ rois,
               float* __restrict__ dst) {
    const int c  = blockIdx.x;
    const int pw = c % 7;
    const int ph = (c / 7) % 7;
    const int t  = threadIdx.x;

    __shared__ float pl[4 * PLANE];
    const RoiGeom g = roi_geom(rois, t);

#pragma unroll
    for (int bb = 0; bb < 4; ++bb) {
        const float4* src = reinterpret_cast<const float4*>(
            feat + ((size_t)bb * CHANNELS + c) * PLANE);
        reinterpret_cast<float4*>(pl + bb * PLANE)[t] = src[t];
    }
    __syncthreads();

    float v = bin_value(g, ph, pw, pl);
    if (TO_WS) dst[(size_t)c * NUM_ROIS + t] = v;
    else       dst[(size_t)t * CHANNELS + c] = v;
}

__global__ __launch_bounds__(256)
void transpose_cn(const float* __restrict__ ws, float* __restrict__ out) {
    __shared__ float tile[32][33];
    const int c0 = blockIdx.y * 32;
    const int n0 = blockIdx.x * 32;
    const int tx = threadIdx.x & 31;
    const int ty = threadIdx.x >> 5;

#pragma unroll
    for (int i = 0; i < 32; i += 8) {
        const int cc = c0 + ty + i;
        if (cc < CHANNELS)
            tile[ty + i][tx] = ws[(size_t)cc * NUM_ROIS + (n0 + tx)];
    }
    __syncthreads();
#pragma unroll
    for (int i = 0; i < 32; i += 8) {
        const int nn = n0 + ty + i;
        const int cc = c0 + tx;
        if (cc < CHANNELS)
            out[(size_t)nn * CHANNELS + cc] = tile[tx][ty + i];
    }
}

extern "C" void kernel_launch(void* const* d_in, const int* in_sizes, int n_in,
                              void* d_out, int out_size, void* d_ws, size_t ws_size,
                              hipStream_t stream) {
    const float* feat = (const float*)d_in[0];
    const float* rois = (const float*)d_in[1];
    float* out = (float*)d_out;

    const size_t need = sizeof(float) * (size_t)CHANNELS * NUM_ROIS;
    if (d_ws != nullptr && ws_size >= need) {
        float* wsp = (float*)d_ws;
        void* args[] = { (void*)&feat, (void*)&rois, (void*)&wsp, (void*)&out };
        hipError_t err = hipLaunchCooperativeKernel(
            (const void*)psroi_fused, dim3(GRID_COOP), dim3(1024), args, 0, stream);
        if (err != hipSuccess) {
            // graph/driver rejected cooperative launch -> proven 2-kernel path
            psroi_lds<true><<<CHANNELS, 1024, 0, stream>>>(feat, rois, wsp);
            transpose_cn<<<dim3(NUM_ROIS / 32, (CHANNELS + 31) / 32), 256, 0, stream>>>(wsp, out);
        }
    } else {
        psroi_lds<false><<<CHANNELS, 1024, 0, stream>>>(feat, rois, out);
    }
}

// Round 3
// 97.546 us; speedup vs baseline: 3.0499x; 3.0499x over previous
//
#include <hip/hip_runtime.h>
#include <math.h>

#define POOLED      7
#define OUTPUT_DIM  21
#define GROUP       7
#define CHANNELS    (OUTPUT_DIM * GROUP * GROUP)   // 1029
#define FH          64
#define FW          64
#define PLANE       (FH * FW)                      // 4096 floats, 16 KB
#define NUM_ROIS    1024
#define SCALE       0.0625f

// Opaque VGPR pin: blocks FMA contraction (hipcc -ffp-contract=fast ignores
// `#pragma clang fp contract(off)`). CORRECTNESS-CRITICAL: the golden's
// boundary chain is f32, separately rounded, with bin = roi * RN(1/7)
// (reciprocal multiply) — verified round 10, absmax 3.9e-3. Do not change.
__device__ __forceinline__ float freeze(float x) {
    __asm__ volatile("" : "+v"(x));
    return x;
}

// ROI-dependent (channel-independent) prefix of the frozen chain.
// Ops are bit-identical to the verified chain.
struct RoiGeom { int b; float start_h, start_w, bin_h, bin_w; };

__device__ __forceinline__ RoiGeom roi_geom(const float* __restrict__ rois, int t) {
    const float* r = rois + t * 5;
    RoiGeom g;
    g.b = (int)r[0];
    float start_w = rintf(r[1]) * SCALE;          // np.round = half-even
    float start_h = rintf(r[2]) * SCALE;
    float end_w   = rintf(r[3] + 1.0f) * SCALE;
    float end_h   = rintf(r[4] + 1.0f) * SCALE;
    float roi_w = fmaxf(end_w - start_w, 0.1f);
    float roi_h = fmaxf(end_h - start_h, 0.1f);
    const float inv7 = 1.0f / 7.0f;               // RN(1/7)
    g.bin_h = freeze(roi_h * inv7);               // reciprocal multiply
    g.bin_w = freeze(roi_w * inv7);
    g.start_h = start_h;
    g.start_w = start_w;
    return g;
}

// ph/pw-dependent tail of the frozen chain + LDS region sum.
__device__ __forceinline__ float bin_value(const RoiGeom& g, int ph, int pw,
                                           const float* __restrict__ pl) {
    float mh0 = freeze((float)ph * g.bin_h);      // separate mul, then add
    float mh1 = freeze((float)(ph + 1) * g.bin_h);
    float mw0 = freeze((float)pw * g.bin_w);
    float mw1 = freeze((float)(pw + 1) * g.bin_w);

    float hs_f = floorf(mh0 + g.start_h);
    float he_f = ceilf (mh1 + g.start_h);
    float ws_f = floorf(mw0 + g.start_w);
    float we_f = ceilf (mw1 + g.start_w);

    int hs = (int)fminf(fmaxf(hs_f, 0.0f), (float)FH);
    int he = (int)fminf(fmaxf(he_f, 0.0f), (float)FH);
    int ws = (int)fminf(fmaxf(ws_f, 0.0f), (float)FW);
    int we = (int)fminf(fmaxf(we_f, 0.0f), (float)FW);

    const float* base = pl + g.b * PLANE;
    float s = 0.0f;
    for (int h = hs; h < he; ++h) {
        const float* row = base + h * FW;
        for (int w = ws; w < we; ++w) s += row[w];
    }
    int area = (he - hs) * (we - ws);
    return (area <= 0) ? 0.0f : s / (float)area;
}

// BIN-MAJOR + LDS-STAGED (round-12 verified structure; round-14 = revert of
// the cooperative-fusion regression + async staging). One block per channel
// c=(d*7+ph)*7+pw; block stages its exclusive 4 planes (64 KB) into LDS.
// 1024 threads (16 waves), 1 ROI/thread; 64 KB LDS => 2 blocks/CU = 32
// waves/CU. grid.sync fusion is BANNED here: R2 measured 214 us with 93%
// occupancy / 2.7% VALU / 2.6% HBM — 16K waves spinning at the global
// barrier across 8 non-coherent XCDs. Two launches are ~10 us; the grid
// sync was ~150 us.
//
// Staging uses global_load_lds width=16 (fire-and-forget into LDS, no VGPR
// round-trip); LDS dest is wave-uniform base + lane*16 (linear in t) as the
// hardware requires. Issued BEFORE the boundary chain so the HBM stream
// overlaps the ROI ALU work.
template<bool TO_WS>
__global__ __launch_bounds__(1024)
void psroi_lds(const float* __restrict__ feat,
               const float* __restrict__ rois,
               float* __restrict__ dst) {
    const int c  = blockIdx.x;            // 0..1028  (== d*49 + ph*7 + pw)
    const int pw = c % 7;
    const int ph = (c / 7) % 7;
    const int t  = threadIdx.x;           // 0..1023 == ROI index

    __shared__ float pl[4 * PLANE];       // 64 KB: 4 batch planes of channel c

    // Stage 4 batch planes of channel c: coalesced 16 B/lane, exactly-once.
#if defined(__has_builtin) && __has_builtin(__builtin_amdgcn_global_load_lds)
    typedef const void __attribute__((address_space(1)))* gas_t;
    typedef void __attribute__((address_space(3)))*       las_t;
#pragma unroll
    for (int bb = 0; bb < 4; ++bb) {
        const float* src = feat + ((size_t)bb * CHANNELS + c) * PLANE + 4 * (size_t)t;
        float* ldst = pl + bb * PLANE + 4 * t;
        __builtin_amdgcn_global_load_lds((gas_t)src, (las_t)ldst, 16, 0, 0);
    }
#else
#pragma unroll
    for (int bb = 0; bb < 4; ++bb) {
        const float4* src = reinterpret_cast<const float4*>(
            feat + ((size_t)bb * CHANNELS + c) * PLANE);
        reinterpret_cast<float4*>(pl + bb * PLANE)[t] = src[t];
    }
#endif

    // Boundary chain overlaps the in-flight staging loads.
    const RoiGeom g = roi_geom(rois, t);

    __syncthreads();                      // compiler drains vmcnt before barrier

    float v = bin_value(g, ph, pw, pl);
    if (TO_WS) dst[(size_t)c * NUM_ROIS + t] = v;   // coalesced 4 KB row
    else       dst[(size_t)t * CHANNELS + c] = v;   // fallback scatter store
}

// ws[1029][1024] -> out[1024][1029]. 32x32 tiles, 256 threads, 33-pad LDS
// (conflict-free column reads). Reads coalesced along n, writes coalesced
// along c (128 B runs per n-row within a tile => no RMW amplification).
// R1-verified byte-for-byte; traffic 4.2 MB in + 4.2 MB out.
__global__ __launch_bounds__(256)
void transpose_cn(const float* __restrict__ ws, float* __restrict__ out) {
    __shared__ float tile[32][33];
    const int c0 = blockIdx.y * 32;
    const int n0 = blockIdx.x * 32;
    const int tx = threadIdx.x & 31;
    const int ty = threadIdx.x >> 5;              // 0..7

#pragma unroll
    for (int i = 0; i < 32; i += 8) {
        const int cc = c0 + ty + i;
        if (cc < CHANNELS)
            tile[ty + i][tx] = ws[(size_t)cc * NUM_ROIS + (n0 + tx)];
    }
    __syncthreads();
#pragma unroll
    for (int i = 0; i < 32; i += 8) {
        const int nn = n0 + ty + i;
        const int cc = c0 + tx;
        if (cc < CHANNELS)
            out[(size_t)nn * CHANNELS + cc] = tile[tx][ty + i];
    }
}

extern "C" void kernel_launch(void* const* d_in, const int* in_sizes, int n_in,
                              void* d_out, int out_size, void* d_ws, size_t ws_size,
                              hipStream_t stream) {
    const float* feat = (const float*)d_in[0];
    const float* rois = (const float*)d_in[1];
    float* out = (float*)d_out;

    const size_t need = sizeof(float) * (size_t)CHANNELS * NUM_ROIS;
    if (d_ws != nullptr && ws_size >= need) {
        float* wsp = (float*)d_ws;
        psroi_lds<true><<<CHANNELS, 1024, 0, stream>>>(feat, rois, wsp);
        transpose_cn<<<dim3(NUM_ROIS / 32, (CHANNELS + 31) / 32), 256, 0, stream>>>(wsp, out);
    } else {
        psroi_lds<false><<<CHANNELS, 1024, 0, stream>>>(feat, rois, out);
    }
}